// Round 1
// baseline (2282.155 us; speedup 1.0000x reference)
//
#include <hip/hip_runtime.h>

// LSTM encoder: B=1024, S=64, H=256.
// Strategy v1: batch-partitioned persistent workgroups.
//   64 WGs x 512 threads; WG g owns batches [16g, 16g+16).
//   Per step: gates(16x1024) = [x_s | h](16x512) @ Wcat^T(512x1024) via
//   mfma_f32_16x16x32_bf16, then elementwise cell. No inter-WG sync needed
//   (LSTM recurrence is batch-independent).
// Weights pre-converted to bf16 in d_ws by prep_kernel: Wcat[g][k], k<256 = W_ih,
//   k>=256 = W_hh (row-major, 4Hx512), plus combined bias (fp32).

typedef __attribute__((ext_vector_type(8))) short short8;
typedef __attribute__((ext_vector_type(4))) float f32x4;

#define B_ 1024
#define S_ 64
#define H_ 256
#define G_ 1024          // 4*H
#define KW 512           // K = [x | h]
#define OUTN (B_*S_*H_)  // 16777216 elements per output tensor
#define APITCH 520       // A-tile row pitch in shorts (+8 pad: bank stride 4 -> 2-way max, free)
#define GPITCH 1032      // gates-tile row pitch in shorts (+8 pad)

__device__ __forceinline__ unsigned short f2bf(float f){
    unsigned int u = __builtin_bit_cast(unsigned int, f);
    u = (u + 0x7fffu + ((u >> 16) & 1u)) >> 16;   // round-to-nearest-even
    return (unsigned short)u;
}
__device__ __forceinline__ float bf2f(unsigned short v){
    unsigned int u = ((unsigned int)v) << 16;
    return __builtin_bit_cast(float, u);
}
__device__ __forceinline__ float sigm(float v){ return 1.0f/(1.0f + __expf(-v)); }
__device__ __forceinline__ float tanh_(float v){ return 2.0f/(1.0f + __expf(-2.0f*v)) - 1.0f; }

__global__ __launch_bounds__(256) void prep_kernel(const float* __restrict__ Wih,
        const float* __restrict__ Whh, const float* __restrict__ bih,
        const float* __restrict__ bhh, unsigned short* __restrict__ Wc,
        float* __restrict__ bias){
    int idx = blockIdx.x*256 + threadIdx.x;
    if (idx < G_*KW){
        int g = idx >> 9, k = idx & 511;
        float v = (k < H_) ? Wih[g*H_ + k] : Whh[g*H_ + (k - H_)];
        Wc[idx] = f2bf(v);
    }
    if (idx < G_) bias[idx] = bih[idx] + bhh[idx];
}

__global__ __launch_bounds__(512) void lstm_kernel(const float* __restrict__ x,
        const float* __restrict__ h0, const float* __restrict__ c0,
        const unsigned short* __restrict__ Wc, const float* __restrict__ bias,
        float* __restrict__ out){
    // LDS: A-tile [16 batches][512 k] bf16 (cols 0..255 = x_s, 256..511 = h)
    //      G-tile [16 batches][1024 gates] bf16
    __shared__ unsigned short At[16*APITCH];   // 16.6 KB
    __shared__ unsigned short Gt[16*GPITCH];   // 33.0 KB

    const int tid  = threadIdx.x;
    const int lane = tid & 63;
    const int w    = tid >> 6;        // wave 0..7, owns gate cols [128w, 128w+128)
    const int b0   = blockIdx.x * 16; // batch base
    const int nl   = lane & 15;       // m (batch) for A / n (gate) for B / col for C
    const int kg   = lane >> 4;       // k-group 0..3

    float creg[8];  // c state, thread-owned (b,d) slots: idx = e*512+tid

    // prologue: h0 -> A-tile h-cols (bf16), c0 -> regs, x[:,0,:] -> A-tile x-cols
    #pragma unroll
    for (int e = 0; e < 8; ++e){
        int idx = e*512 + tid;
        int b = idx >> 8, d = idx & 255;
        At[b*APITCH + H_ + d] = f2bf(h0[(b0+b)*H_ + d]);
        creg[e] = c0[(b0+b)*H_ + d];
        At[b*APITCH + d] = f2bf(x[((b0+b)*S_ + 0)*H_ + d]);
    }
    float bias_l[8];
    #pragma unroll
    for (int t = 0; t < 8; ++t) bias_l[t] = bias[w*128 + t*16 + nl];
    __syncthreads();

    #pragma unroll 1
    for (int s = 0; s < S_; ++s){
        // ---- gates = A @ Wcat^T  (per wave: M=16, N=128, K=512) ----
        f32x4 acc[8] = {};
        const unsigned short* Arow  = At + nl*APITCH + kg*8;
        const unsigned short* Wbase = Wc + (w*128 + nl)*KW + kg*8;
        #pragma unroll
        for (int kf = 0; kf < 16; ++kf){
            short8 a = *(const short8*)(Arow + kf*32);
            #pragma unroll
            for (int t = 0; t < 8; ++t){
                short8 bv = *(const short8*)(Wbase + t*16*KW + kf*32);
                acc[t] = __builtin_amdgcn_mfma_f32_16x16x32_bf16(a, bv, acc[t], 0, 0, 0);
            }
        }
        // C layout: col = lane&15, row = (lane>>4)*4 + j  (row = batch, col = gate)
        #pragma unroll
        for (int t = 0; t < 8; ++t){
            #pragma unroll
            for (int j = 0; j < 4; ++j){
                Gt[(kg*4 + j)*GPITCH + w*128 + t*16 + nl] = f2bf(acc[t][j] + bias_l[t]);
            }
        }
        __syncthreads();

        // ---- elementwise cell + h/out writes + next-x prefetch ----
        #pragma unroll
        for (int e = 0; e < 8; ++e){
            int idx = e*512 + tid;
            int b = idx >> 8, d = idx & 255;
            float iv = bf2f(Gt[b*GPITCH + d]);
            float fv = bf2f(Gt[b*GPITCH + H_ + d]);
            float gv = bf2f(Gt[b*GPITCH + 2*H_ + d]);
            float ov = bf2f(Gt[b*GPITCH + 3*H_ + d]);
            float cn = sigm(fv)*creg[e] + sigm(iv)*tanh_(gv);
            float hn = sigm(ov)*tanh_(cn);
            creg[e] = cn;
            At[b*APITCH + H_ + d] = f2bf(hn);
            int oidx = ((b0+b)*S_ + s)*H_ + d;
            out[oidx] = hn;          // outputs
            out[OUTN + oidx] = hn;   // hiddens (identical data)
            if (s + 1 < S_) At[b*APITCH + d] = f2bf(x[((b0+b)*S_ + (s+1))*H_ + d]);
        }
        __syncthreads();
    }
}

extern "C" void kernel_launch(void* const* d_in, const int* in_sizes, int n_in,
                              void* d_out, int out_size, void* d_ws, size_t ws_size,
                              hipStream_t stream){
    const float* x   = (const float*)d_in[0];
    const float* h0  = (const float*)d_in[1];
    const float* c0  = (const float*)d_in[2];
    const float* Wih = (const float*)d_in[3];
    const float* Whh = (const float*)d_in[4];
    const float* bih = (const float*)d_in[5];
    const float* bhh = (const float*)d_in[6];
    // d_in[7] = seq_length (==64, fixed by problem shape; not read from device)

    unsigned short* Wc = (unsigned short*)d_ws;                 // 1 MB bf16 weights
    float* bias = (float*)((char*)d_ws + (size_t)G_*KW*2);      // 4 KB fp32 bias

    prep_kernel<<<(G_*KW + 255)/256, 256, 0, stream>>>(Wih, Whh, bih, bhh, Wc, bias);
    lstm_kernel<<<64, 512, 0, stream>>>(x, h0, c0, Wc, bias, (float*)d_out);
}

// Round 2
// 1371.579 us; speedup vs baseline: 1.6639x; 1.6639x over previous
//
#include <hip/hip_runtime.h>

// LSTM encoder B=1024,S=64,H=256 — v2: weight-in-register cluster design.
// 32 clusters x 8 WGs x 512 threads. Cluster owns 32 batches; WG owns 32 h-dims
// (128 gate rows). Each wave holds its MFMA B-fragments (N=32,K=512) in VGPRs
// permanently (128 VGPRs). Per step: gates = [x_s|h](32x512) @ Wslice^T via
// mfma_f32_16x16x32_bf16, cell elementwise, h exchanged via global bf16
// double buffer + per-cluster atomic barrier (device-scope fences).

typedef __attribute__((ext_vector_type(8))) short short8;
typedef __attribute__((ext_vector_type(4))) float f32x4;

#define B_ 1024
#define S_ 64
#define H_ 256
#define G_ 1024
#define KW 512
#define OUTN (B_*S_*H_)
#define APITCH 520      // A-tile pitch (shorts): +8 pad -> 2-way max on frag reads
#define GPITCH 132      // gates tile pitch (floats)
#define NCL 32
#define CWG 8

__device__ __forceinline__ unsigned short f2bf(float f){
    unsigned int u = __builtin_bit_cast(unsigned int, f);
    u = (u + 0x7fffu + ((u >> 16) & 1u)) >> 16;   // RNE
    return (unsigned short)u;
}
__device__ __forceinline__ float sigm(float v){ return 1.0f/(1.0f + __expf(-v)); }
__device__ __forceinline__ float tanh_(float v){ return 2.0f/(1.0f + __expf(-2.0f*v)) - 1.0f; }

__global__ __launch_bounds__(256) void prep_kernel(const float* __restrict__ Wih,
        const float* __restrict__ Whh, const float* __restrict__ bih,
        const float* __restrict__ bhh, const float* __restrict__ h0,
        unsigned short* __restrict__ Wc, float* __restrict__ bias,
        unsigned short* __restrict__ hbuf, unsigned int* __restrict__ cnt){
    int idx = blockIdx.x*256 + threadIdx.x;
    if (idx < G_*KW){
        int g = idx >> 9, k = idx & 511;
        float v = (k < H_) ? Wih[g*H_ + k] : Whh[g*H_ + (k - H_)];
        Wc[idx] = f2bf(v);
    }
    if (idx < B_*H_) hbuf[idx] = f2bf(h0[idx]);   // h(0), buffer 0
    if (idx < G_) bias[idx] = bih[idx] + bhh[idx];
    if (idx < NCL) cnt[idx] = 0u;
}

__global__ __launch_bounds__(512, 2) void lstm_kernel(
        const float* __restrict__ x, const float* __restrict__ c0,
        const unsigned short* __restrict__ Wc, const float* __restrict__ bias,
        unsigned short* __restrict__ hbuf,      // [2][B][H] bf16
        unsigned int* __restrict__ cnt,         // [NCL]
        float* __restrict__ out){
    __shared__ unsigned short At[32*APITCH];    // 33,280 B  [batch][k: 0..255=x, 256..511=h]
    __shared__ float Gt[32*GPITCH];             // 16,896 B  [batch][128 gate rows]

    const int tid  = threadIdx.x;
    const int lane = tid & 63;
    const int w    = tid >> 6;
    const int wm   = w >> 2;          // 0..1: batch half
    const int wn   = w & 3;           // 0..3: gate type (i,f,g,o)
    const int nl   = lane & 15;
    const int kg   = lane >> 4;
    const int bid  = blockIdx.x;
    const int cl   = bid & (NCL-1);   // cluster; WGs {cl, cl+32,...} share bid%8 -> same XCD
    const int j    = bid >> 5;        // wg-in-cluster 0..7
    const int b0   = cl * 32;
    const int d0   = j * 32;

    // ---- persistent W fragments: wave holds rows g = wn*256 + d0 + tn*16 + nl ----
    short8 wf[2][16];                 // 128 VGPRs
    float bias_l[2];
    #pragma unroll
    for (int tn = 0; tn < 2; ++tn){
        int g = wn*256 + d0 + tn*16 + nl;
        const unsigned short* wp = Wc + (size_t)g*KW + kg*8;
        #pragma unroll
        for (int kf = 0; kf < 16; ++kf)
            wf[tn][kf] = *(const short8*)(wp + kf*32);
        bias_l[tn] = bias[g];
    }

    // ---- per-thread cell slot: batch sb, dim pair (2*dp, 2*dp+1) ----
    const int sb = tid >> 4;          // 0..31
    const int dp = tid & 15;          // 0..15
    float c0r, c1r;
    {
        float2 cv = *(const float2*)(c0 + (size_t)(b0+sb)*H_ + d0 + 2*dp);
        c0r = cv.x; c1r = cv.y;
    }

    // ---- prologue: stage x(0) and h(0) ----
    float xr[16];
    {
        const float* xp = x + ((size_t)(b0+sb)*S_ + 0)*H_ + dp*16;
        #pragma unroll
        for (int q = 0; q < 4; ++q){
            f32x4 v = *(const f32x4*)(xp + q*4);
            xr[q*4+0]=v[0]; xr[q*4+1]=v[1]; xr[q*4+2]=v[2]; xr[q*4+3]=v[3];
        }
        unsigned short tmp[16];
        #pragma unroll
        for (int q = 0; q < 16; ++q) tmp[q] = f2bf(xr[q]);
        *(short8*)(At + sb*APITCH + dp*16)     = *(const short8*)tmp;
        *(short8*)(At + sb*APITCH + dp*16 + 8) = *(const short8*)(tmp+8);
    }
    {
        const unsigned short* hp = hbuf + (size_t)(b0+sb)*H_ + dp*16;
        *(short8*)(At + sb*APITCH + H_ + dp*16)     = *(const short8*)hp;
        *(short8*)(At + sb*APITCH + H_ + dp*16 + 8) = *(const short8*)(hp+8);
    }
    // prefetch x(1)
    {
        const float* xp = x + ((size_t)(b0+sb)*S_ + 1)*H_ + dp*16;
        #pragma unroll
        for (int q = 0; q < 4; ++q){
            f32x4 v = *(const f32x4*)(xp + q*4);
            xr[q*4+0]=v[0]; xr[q*4+1]=v[1]; xr[q*4+2]=v[2]; xr[q*4+3]=v[3];
        }
    }
    __syncthreads();

    #pragma unroll 1
    for (int s = 0; s < S_; ++s){
        // ---- MFMA: gates(32 x 128) += A(32x512) @ Wslice^T ----
        f32x4 acc[2];
        #pragma unroll
        for (int tn = 0; tn < 2; ++tn)
            acc[tn] = (f32x4){bias_l[tn], bias_l[tn], bias_l[tn], bias_l[tn]};
        const unsigned short* ar = At + (wm*16 + nl)*APITCH + kg*8;
        #pragma unroll
        for (int kf = 0; kf < 16; ++kf){
            short8 av = *(const short8*)(ar + kf*32);
            acc[0] = __builtin_amdgcn_mfma_f32_16x16x32_bf16(av, wf[0][kf], acc[0], 0, 0, 0);
            acc[1] = __builtin_amdgcn_mfma_f32_16x16x32_bf16(av, wf[1][kf], acc[1], 0, 0, 0);
        }
        #pragma unroll
        for (int tn = 0; tn < 2; ++tn)
            #pragma unroll
            for (int jj = 0; jj < 4; ++jj)
                Gt[(wm*16 + kg*4 + jj)*GPITCH + wn*32 + tn*16 + nl] = acc[tn][jj];
        __syncthreads();   // sync1: Gt ready, At free

        // ---- restage x(s+1) (held in xr), prefetch x(s+2) ----
        if (s + 1 < S_){
            unsigned short tmp[16];
            #pragma unroll
            for (int q = 0; q < 16; ++q) tmp[q] = f2bf(xr[q]);
            *(short8*)(At + sb*APITCH + dp*16)     = *(const short8*)tmp;
            *(short8*)(At + sb*APITCH + dp*16 + 8) = *(const short8*)(tmp+8);
        }
        if (s + 2 < S_){
            const float* xp = x + ((size_t)(b0+sb)*S_ + (s+2))*H_ + dp*16;
            #pragma unroll
            for (int q = 0; q < 4; ++q){
                f32x4 v = *(const f32x4*)(xp + q*4);
                xr[q*4+0]=v[0]; xr[q*4+1]=v[1]; xr[q*4+2]=v[2]; xr[q*4+3]=v[3];
            }
        }

        // ---- cell update (thread owns batch sb, dims 2dp, 2dp+1) ----
        {
            const float* gr = Gt + sb*GPITCH + 2*dp;
            float iv0 = gr[0],  iv1 = gr[1];
            float fv0 = gr[32], fv1 = gr[33];
            float gv0 = gr[64], gv1 = gr[65];
            float ov0 = gr[96], ov1 = gr[97];
            float cn0 = sigm(fv0)*c0r + sigm(iv0)*tanh_(gv0);
            float cn1 = sigm(fv1)*c1r + sigm(iv1)*tanh_(gv1);
            float hn0 = sigm(ov0)*tanh_(cn0);
            float hn1 = sigm(ov1)*tanh_(cn1);
            c0r = cn0; c1r = cn1;
            unsigned int hpk = (unsigned int)f2bf(hn0) | ((unsigned int)f2bf(hn1) << 16);
            unsigned short* hnext = hbuf + (size_t)((s+1)&1)*(B_*H_);
            *(unsigned int*)(hnext + (size_t)(b0+sb)*H_ + d0 + 2*dp) = hpk;
            size_t o = ((size_t)(b0+sb)*S_ + s)*H_ + d0 + 2*dp;
            float2 hv; hv.x = hn0; hv.y = hn1;
            *(float2*)(out + o) = hv;
            *(float2*)(out + OUTN + o) = hv;
        }

        if (s == S_-1) break;

        __syncthreads();   // sync2: all h stores drained (syncthreads waits vmcnt)

        // ---- cluster barrier: 8 WGs ----
        if (tid == 0){
            __threadfence();                     // release (publish h slice)
            atomicAdd(&cnt[cl], 1u);
            unsigned int tgt = CWG * (unsigned int)(s + 1);
            int guard = 0;
            while (__hip_atomic_load(&cnt[cl], __ATOMIC_RELAXED, __HIP_MEMORY_SCOPE_AGENT) < tgt){
                __builtin_amdgcn_s_sleep(1);
                if (++guard > (1<<24)) break;    // fail loud (absmax) instead of hang
            }
            __threadfence();                     // acquire
        }
        __syncthreads();   // sync3: whole WG released

        // ---- stage h(s+1) ----
        {
            const unsigned short* hp = hbuf + (size_t)((s+1)&1)*(B_*H_)
                                     + (size_t)(b0+sb)*H_ + dp*16;
            *(short8*)(At + sb*APITCH + H_ + dp*16)     = *(const short8*)hp;
            *(short8*)(At + sb*APITCH + H_ + dp*16 + 8) = *(const short8*)(hp+8);
        }
        __syncthreads();   // sync4: A-tile complete for s+1
    }
}

extern "C" void kernel_launch(void* const* d_in, const int* in_sizes, int n_in,
                              void* d_out, int out_size, void* d_ws, size_t ws_size,
                              hipStream_t stream){
    const float* x   = (const float*)d_in[0];
    const float* h0  = (const float*)d_in[1];
    const float* c0  = (const float*)d_in[2];
    const float* Wih = (const float*)d_in[3];
    const float* Whh = (const float*)d_in[4];
    const float* bih = (const float*)d_in[5];
    const float* bhh = (const float*)d_in[6];

    unsigned short* Wc   = (unsigned short*)d_ws;                        // 1 MB @ 0
    float*          bias = (float*)((char*)d_ws + 0x100000);             // 4 KB
    unsigned int*   cnt  = (unsigned int*)((char*)d_ws + 0x101000);      // 128 B
    unsigned short* hbuf = (unsigned short*)((char*)d_ws + 0x102000);    // 1 MB (2 bufs)
    float*          outp = (float*)d_out;

    prep_kernel<<<(G_*KW + 255)/256, 256, 0, stream>>>(Wih, Whh, bih, bhh, h0, Wc, bias, hbuf, cnt);

    void* args[] = {(void*)&x, (void*)&c0, (void*)&Wc, (void*)&bias,
                    (void*)&hbuf, (void*)&cnt, (void*)&outp};
    hipLaunchCooperativeKernel((void*)lstm_kernel, dim3(NCL*CWG), dim3(512), args, 0, stream);
}

// Round 3
// 422.312 us; speedup vs baseline: 5.4040x; 3.2478x over previous
//
#include <hip/hip_runtime.h>

// LSTM encoder B=1024,S=64,H=256 — v3: register-resident weights (forced) +
// fence-free cluster sync via relaxed agent-scope atomics.
// 32 clusters x 8 WGs x 512 threads (grid=256 = 1 WG/CU, cooperative).
// Cluster owns 32 batches; WG owns 32 h-dims (128 gate rows); each of 8 waves
// owns 16 gate rows (wf[16] = 64 VGPRs, pinned with asm) and computes M=32.
// h exchanged via global bf16 double buffer with relaxed agent atomics; no
// __threadfence (no buffer_wbl2/inv) anywhere in the loop.

typedef __attribute__((ext_vector_type(8))) short short8;
typedef __attribute__((ext_vector_type(4))) float f32x4;
typedef unsigned long long u64;
typedef unsigned int u32;
typedef unsigned short u16;

#define B_ 1024
#define S_ 64
#define H_ 256
#define G_ 1024
#define KW 512
#define OUTN (B_*S_*H_)
#define APITCH 520      // A-tile pitch (shorts), +8 pad
#define GPITCH 132      // gates tile pitch (floats), +4 pad
#define NCL 32
#define CWG 8

__device__ __forceinline__ u16 f2bf(float f){
    u32 u = __builtin_bit_cast(u32, f);
    u = (u + 0x7fffu + ((u >> 16) & 1u)) >> 16;   // RNE
    return (u16)u;
}
__device__ __forceinline__ float sigm(float v){ return 1.0f/(1.0f + __expf(-v)); }
__device__ __forceinline__ float tanh_(float v){ return 2.0f/(1.0f + __expf(-2.0f*v)) - 1.0f; }

__global__ __launch_bounds__(256) void prep_kernel(const float* __restrict__ Wih,
        const float* __restrict__ Whh, const float* __restrict__ bih,
        const float* __restrict__ bhh, const float* __restrict__ h0,
        u16* __restrict__ Wc, float* __restrict__ bias,
        u16* __restrict__ hbuf, u32* __restrict__ cnt){
    int idx = blockIdx.x*256 + threadIdx.x;
    if (idx < G_*KW){
        int g = idx >> 9, k = idx & 511;
        float v = (k < H_) ? Wih[g*H_ + k] : Whh[g*H_ + (k - H_)];
        Wc[idx] = f2bf(v);
    }
    if (idx < B_*H_) hbuf[idx] = f2bf(h0[idx]);   // h(0) -> buffer 0
    if (idx < G_) bias[idx] = bih[idx] + bhh[idx];
    if (idx < NCL) cnt[idx] = 0u;
}

__global__ __launch_bounds__(512, 2) void lstm_kernel(
        const float* __restrict__ x, const float* __restrict__ c0,
        const u16* __restrict__ Wc, const float* __restrict__ bias,
        u16* hbuf, u32* cnt, float* __restrict__ out){
    __shared__ u16 At[32*APITCH];    // 33,280 B  [batch][k: 0..255=x, 256..511=h]
    __shared__ float Gt[32*GPITCH];  // 16,896 B  [batch][128 gate cols: i|f|g|o x 32]

    const int tid  = threadIdx.x;
    const int lane = tid & 63;
    const int w    = tid >> 6;
    const int wn   = w >> 1;          // gate type 0..3
    const int tn   = w & 1;           // 16-row half within the WG's 32 dims
    const int nl   = lane & 15;
    const int kg   = lane >> 4;
    const int bid  = blockIdx.x;
    const int cl   = bid & (NCL-1);   // cluster
    const int j    = bid >> 5;        // wg-in-cluster 0..7
    const int b0   = cl * 32;
    const int d0   = j * 32;

    // ---- persistent W: wave holds gate row g (one row per lane-col nl) ----
    const int g = wn*256 + d0 + tn*16 + nl;
    short8 wf[16];                    // 64 VGPRs
    {
        const u16* wp = Wc + (size_t)g*KW + kg*8;
        #pragma unroll
        for (int kf = 0; kf < 16; ++kf) wf[kf] = *(const short8*)(wp + kf*32);
    }
    #pragma unroll
    for (int kf = 0; kf < 16; ++kf) asm volatile("" : "+v"(wf[kf]));  // pin: no remat
    const float bias_l = bias[g];

    // ---- per-thread cell slot: batch sb, dims (d0+2dp, d0+2dp+1) ----
    const int sb = tid >> 4;          // 0..31
    const int dp = tid & 15;          // 0..15
    float c0r, c1r;
    {
        float2 cv = *(const float2*)(c0 + (size_t)(b0+sb)*H_ + d0 + 2*dp);
        c0r = cv.x; c1r = cv.y;
    }

    // ---- prologue: stage x(0), h(0); prefetch x(1) ----
    float xr[16];
    {
        const float* xp = x + ((size_t)(b0+sb)*S_ + 0)*H_ + dp*16;
        #pragma unroll
        for (int q = 0; q < 4; ++q){
            f32x4 v = *(const f32x4*)(xp + q*4);
            xr[q*4+0]=v[0]; xr[q*4+1]=v[1]; xr[q*4+2]=v[2]; xr[q*4+3]=v[3];
        }
        u16 tmp[16];
        #pragma unroll
        for (int q = 0; q < 16; ++q) tmp[q] = f2bf(xr[q]);
        *(short8*)(At + sb*APITCH + dp*16)     = *(const short8*)tmp;
        *(short8*)(At + sb*APITCH + dp*16 + 8) = *(const short8*)(tmp+8);
    }
    {
        const u16* hp = hbuf + (size_t)(b0+sb)*H_ + dp*16;   // plain: kernel-boundary coherent
        *(short8*)(At + sb*APITCH + H_ + dp*16)     = *(const short8*)hp;
        *(short8*)(At + sb*APITCH + H_ + dp*16 + 8) = *(const short8*)(hp+8);
    }
    {
        const float* xp = x + ((size_t)(b0+sb)*S_ + 1)*H_ + dp*16;
        #pragma unroll
        for (int q = 0; q < 4; ++q){
            f32x4 v = *(const f32x4*)(xp + q*4);
            xr[q*4+0]=v[0]; xr[q*4+1]=v[1]; xr[q*4+2]=v[2]; xr[q*4+3]=v[3];
        }
    }
    __syncthreads();

    #pragma unroll 1
    for (int s = 0; s < S_; ++s){
        // ---- MFMA: gates(32 x 16-per-wave) = A(32x512) @ wf^T ----
        f32x4 acc0 = (f32x4){bias_l, bias_l, bias_l, bias_l};
        f32x4 acc1 = acc0;
        const u16* ar = At + nl*APITCH + kg*8;
        #pragma unroll
        for (int kf = 0; kf < 16; ++kf){
            short8 a0 = *(const short8*)(ar + kf*32);
            short8 a1 = *(const short8*)(ar + 16*APITCH + kf*32);
            acc0 = __builtin_amdgcn_mfma_f32_16x16x32_bf16(a0, wf[kf], acc0, 0, 0, 0);
            acc1 = __builtin_amdgcn_mfma_f32_16x16x32_bf16(a1, wf[kf], acc1, 0, 0, 0);
        }
        const int colc = wn*32 + tn*16 + nl;
        #pragma unroll
        for (int jj = 0; jj < 4; ++jj){
            Gt[(kg*4 + jj)*GPITCH + colc]        = acc0[jj];   // batches 0..15
            Gt[(16 + kg*4 + jj)*GPITCH + colc]   = acc1[jj];   // batches 16..31
        }
        __syncthreads();   // sync1: Gt ready, At free

        // ---- restage x(s+1) (in xr) ----
        if (s + 1 < S_){
            u16 tmp[16];
            #pragma unroll
            for (int q = 0; q < 16; ++q) tmp[q] = f2bf(xr[q]);
            *(short8*)(At + sb*APITCH + dp*16)     = *(const short8*)tmp;
            *(short8*)(At + sb*APITCH + dp*16 + 8) = *(const short8*)(tmp+8);
        }

        // ---- cell update ----
        u16* hnext = hbuf + (size_t)((s+1)&1)*(B_*H_);
        {
            const float* gr = Gt + sb*GPITCH + 2*dp;
            float iv0 = gr[0],  iv1 = gr[1];
            float fv0 = gr[32], fv1 = gr[33];
            float gv0 = gr[64], gv1 = gr[65];
            float ov0 = gr[96], ov1 = gr[97];
            float cn0 = sigm(fv0)*c0r + sigm(iv0)*tanh_(gv0);
            float cn1 = sigm(fv1)*c1r + sigm(iv1)*tanh_(gv1);
            float hn0 = sigm(ov0)*tanh_(cn0);
            float hn1 = sigm(ov1)*tanh_(cn1);
            c0r = cn0; c1r = cn1;
            u32 hpk = (u32)f2bf(hn0) | ((u32)f2bf(hn1) << 16);
            // publish h pair at the device coherence point (no fence needed)
            __hip_atomic_store((u32*)(hnext + (size_t)(b0+sb)*H_ + d0 + 2*dp), hpk,
                               __ATOMIC_RELAXED, __HIP_MEMORY_SCOPE_AGENT);
            // own slice of next A-tile straight from registers
            *(u32*)(At + sb*APITCH + H_ + d0 + 2*dp) = hpk;
            size_t o = ((size_t)(b0+sb)*S_ + s)*H_ + d0 + 2*dp;
            float2 hv; hv.x = hn0; hv.y = hn1;
            *(float2*)(out + o) = hv;
            *(float2*)(out + OUTN + o) = hv;
        }

        if (s == S_-1) break;

        __syncthreads();   // sync2: every thread's h stores drained (vmcnt 0)

        if (tid == 0)
            __hip_atomic_fetch_add(&cnt[cl], 1u, __ATOMIC_RELAXED, __HIP_MEMORY_SCOPE_AGENT);

        // prefetch x(s+2): in flight during the spin
        if (s + 2 < S_){
            const float* xp = x + ((size_t)(b0+sb)*S_ + (s+2))*H_ + dp*16;
            #pragma unroll
            for (int q = 0; q < 4; ++q){
                f32x4 v = *(const f32x4*)(xp + q*4);
                xr[q*4+0]=v[0]; xr[q*4+1]=v[1]; xr[q*4+2]=v[2]; xr[q*4+3]=v[3];
            }
        }

        if (tid == 0){
            u32 tgt = CWG * (u32)(s + 1);
            int guard = 0;
            while (__hip_atomic_load(&cnt[cl], __ATOMIC_RELAXED, __HIP_MEMORY_SCOPE_AGENT) < tgt){
                __builtin_amdgcn_s_sleep(1);
                if (++guard > (1<<20)) break;   // fail loud, don't hang
            }
        }
        __syncthreads();   // sync3: WG released

        // ---- stage h(s+1), skipping own 32-dim chunk (already in At) ----
        if ((dp >> 1) != j){
            const u64* hp = (const u64*)(hnext + (size_t)(b0+sb)*H_ + dp*16);
            u64 v0 = __hip_atomic_load(hp+0, __ATOMIC_RELAXED, __HIP_MEMORY_SCOPE_AGENT);
            u64 v1 = __hip_atomic_load(hp+1, __ATOMIC_RELAXED, __HIP_MEMORY_SCOPE_AGENT);
            u64 v2 = __hip_atomic_load(hp+2, __ATOMIC_RELAXED, __HIP_MEMORY_SCOPE_AGENT);
            u64 v3 = __hip_atomic_load(hp+3, __ATOMIC_RELAXED, __HIP_MEMORY_SCOPE_AGENT);
            u64* dst = (u64*)(At + sb*APITCH + H_ + dp*16);
            dst[0] = v0; dst[1] = v1; dst[2] = v2; dst[3] = v3;
        }
        __syncthreads();   // sync4: A-tile complete for s+1
    }
}

extern "C" void kernel_launch(void* const* d_in, const int* in_sizes, int n_in,
                              void* d_out, int out_size, void* d_ws, size_t ws_size,
                              hipStream_t stream){
    const float* x   = (const float*)d_in[0];
    const float* h0  = (const float*)d_in[1];
    const float* c0  = (const float*)d_in[2];
    const float* Wih = (const float*)d_in[3];
    const float* Whh = (const float*)d_in[4];
    const float* bih = (const float*)d_in[5];
    const float* bhh = (const float*)d_in[6];

    u16*   Wc   = (u16*)d_ws;                          // 1 MB @ 0
    float* bias = (float*)((char*)d_ws + 0x100000);    // 4 KB
    u32*   cnt  = (u32*)((char*)d_ws + 0x101000);      // 128 B
    u16*   hbuf = (u16*)((char*)d_ws + 0x102000);      // 1 MB (double buffer)
    float* outp = (float*)d_out;

    prep_kernel<<<(G_*KW + 255)/256, 256, 0, stream>>>(Wih, Whh, bih, bhh, h0, Wc, bias, hbuf, cnt);

    void* args[] = {(void*)&x, (void*)&c0, (void*)&Wc, (void*)&bias,
                    (void*)&hbuf, (void*)&cnt, (void*)&outp};
    hipLaunchCooperativeKernel((void*)lstm_kernel, dim3(NCL*CWG), dim3(512), args, 0, stream);
}

// Round 4
// 231.544 us; speedup vs baseline: 9.8563x; 1.8239x over previous
//
#include <hip/hip_runtime.h>

// LSTM encoder B=1024,S=64,H=256 — v4: flag-sync + work-under-the-wait.
// 32 clusters x 8 WGs x 512 threads (cooperative, 1 WG/CU). Cluster owns 32
// batches; WG owns 32 h-dims (128 gate rows); each wave owns 16 gate rows in
// registers (wf[16], pinned). Per-step sync via per-WG step flags (relaxed
// agent atomics, no RMW, no fences). The x-part of the next step's gates
// (K=0..255) is computed between flag-publish and poll, hiding the wait.

typedef __attribute__((ext_vector_type(8))) short short8;
typedef __attribute__((ext_vector_type(4))) float f32x4;
typedef unsigned long long u64;
typedef unsigned int u32;
typedef unsigned short u16;

#define B_ 1024
#define S_ 64
#define H_ 256
#define G_ 1024
#define KW 512
#define OUTN (B_*S_*H_)
#define APITCH 520      // A-tile pitch (shorts), +8 pad
#define GPITCH 132      // gates tile pitch (floats), +4 pad
#define NCL 32
#define CWG 8

__device__ __forceinline__ u16 f2bf(float f){
    u32 u = __builtin_bit_cast(u32, f);
    u = (u + 0x7fffu + ((u >> 16) & 1u)) >> 16;   // RNE
    return (u16)u;
}
__device__ __forceinline__ float sigm(float v){ return 1.0f/(1.0f + __expf(-v)); }
__device__ __forceinline__ float tanh_(float v){ return 2.0f/(1.0f + __expf(-2.0f*v)) - 1.0f; }

__global__ __launch_bounds__(256) void prep_kernel(const float* __restrict__ Wih,
        const float* __restrict__ Whh, const float* __restrict__ bih,
        const float* __restrict__ bhh, const float* __restrict__ h0,
        u16* __restrict__ Wc, float* __restrict__ bias,
        u16* __restrict__ hbuf, u32* __restrict__ flg){
    int idx = blockIdx.x*256 + threadIdx.x;
    if (idx < G_*KW){
        int g = idx >> 9, k = idx & 511;
        float v = (k < H_) ? Wih[g*H_ + k] : Whh[g*H_ + (k - H_)];
        Wc[idx] = f2bf(v);
    }
    if (idx < B_*H_) hbuf[idx] = f2bf(h0[idx]);   // h(0) -> buffer 0
    if (idx < G_) bias[idx] = bih[idx] + bhh[idx];
    if (idx < NCL*CWG) flg[idx] = 0u;
}

__global__ __launch_bounds__(512, 2) void lstm_kernel(
        const float* __restrict__ x, const float* __restrict__ c0,
        const u16* __restrict__ Wc, const float* __restrict__ bias,
        u16* hbuf, u32* flg, float* __restrict__ out){
    __shared__ u16 At[32*APITCH];    // [batch][k: 0..255=x, 256..511=h]
    __shared__ float Gt[32*GPITCH];  // [batch][128 gate cols: i|f|g|o x 32]

    const int tid  = threadIdx.x;
    const int lane = tid & 63;
    const int w    = tid >> 6;
    const int wn   = w >> 1;          // gate type 0..3
    const int tn   = w & 1;           // 16-row half of the WG's 32 dims
    const int nl   = lane & 15;
    const int kg   = lane >> 4;
    const int bid  = blockIdx.x;
    const int cl   = bid & (NCL-1);
    const int j    = bid >> 5;        // wg-in-cluster 0..7
    const int b0   = cl * 32;
    const int d0   = j * 32;

    // ---- persistent W: wave holds 16 gate rows (one per lane-col nl) ----
    const int g = wn*256 + d0 + tn*16 + nl;
    short8 wf[16];                    // 64 VGPRs
    {
        const u16* wp = Wc + (size_t)g*KW + kg*8;
        #pragma unroll
        for (int kf = 0; kf < 16; ++kf) wf[kf] = *(const short8*)(wp + kf*32);
    }
    #pragma unroll
    for (int kf = 0; kf < 16; ++kf) asm volatile("" : "+v"(wf[kf]));  // pin
    const float bias_l = bias[g];

    // ---- per-thread cell slot: batch sb, dims (d0+2dp, d0+2dp+1) ----
    const int sb = tid >> 4;          // 0..31
    const int dp = tid & 15;          // 0..15
    float c0r, c1r;
    {
        float2 cv = *(const float2*)(c0 + (size_t)(b0+sb)*H_ + d0 + 2*dp);
        c0r = cv.x; c1r = cv.y;
    }

    // ---- prologue: stage x(0), h(0); prefetch x(1) ----
    float xr[16];
    {
        const float* xp = x + ((size_t)(b0+sb)*S_ + 0)*H_ + dp*16;
        #pragma unroll
        for (int q = 0; q < 4; ++q){
            f32x4 v = *(const f32x4*)(xp + q*4);
            xr[q*4+0]=v[0]; xr[q*4+1]=v[1]; xr[q*4+2]=v[2]; xr[q*4+3]=v[3];
        }
        u16 tmp[16];
        #pragma unroll
        for (int q = 0; q < 16; ++q) tmp[q] = f2bf(xr[q]);
        *(short8*)(At + sb*APITCH + dp*16)     = *(const short8*)tmp;
        *(short8*)(At + sb*APITCH + dp*16 + 8) = *(const short8*)(tmp+8);
    }
    {
        const u16* hp = hbuf + (size_t)(b0+sb)*H_ + dp*16;   // kernel-boundary coherent
        *(short8*)(At + sb*APITCH + H_ + dp*16)     = *(const short8*)hp;
        *(short8*)(At + sb*APITCH + H_ + dp*16 + 8) = *(const short8*)(hp+8);
    }
    {
        const float* xp = x + ((size_t)(b0+sb)*S_ + 1)*H_ + dp*16;
        #pragma unroll
        for (int q = 0; q < 4; ++q){
            f32x4 v = *(const f32x4*)(xp + q*4);
            xr[q*4+0]=v[0]; xr[q*4+1]=v[1]; xr[q*4+2]=v[2]; xr[q*4+3]=v[3];
        }
    }
    __syncthreads();

    // ---- x-part of step 0 gates (kf 0..7 over x(0)) ----
    f32x4 acc0 = (f32x4){bias_l, bias_l, bias_l, bias_l};
    f32x4 acc1 = acc0;
    {
        const u16* ar = At + nl*APITCH + kg*8;
        #pragma unroll
        for (int kf = 0; kf < 8; ++kf){
            short8 a0 = *(const short8*)(ar + kf*32);
            short8 a1 = *(const short8*)(ar + 16*APITCH + kf*32);
            acc0 = __builtin_amdgcn_mfma_f32_16x16x32_bf16(a0, wf[kf], acc0, 0, 0, 0);
            acc1 = __builtin_amdgcn_mfma_f32_16x16x32_bf16(a1, wf[kf], acc1, 0, 0, 0);
        }
    }

    #pragma unroll 1
    for (int s = 0; s < S_; ++s){
        // ---- h-part: kf 8..15 over h(s) ----
        {
            const u16* ar = At + nl*APITCH + kg*8;
            #pragma unroll
            for (int kf = 8; kf < 16; ++kf){
                short8 a0 = *(const short8*)(ar + kf*32);
                short8 a1 = *(const short8*)(ar + 16*APITCH + kf*32);
                acc0 = __builtin_amdgcn_mfma_f32_16x16x32_bf16(a0, wf[kf], acc0, 0, 0, 0);
                acc1 = __builtin_amdgcn_mfma_f32_16x16x32_bf16(a1, wf[kf], acc1, 0, 0, 0);
            }
        }
        const int colc = wn*32 + tn*16 + nl;
        #pragma unroll
        for (int jj = 0; jj < 4; ++jj){
            Gt[(kg*4 + jj)*GPITCH + colc]      = acc0[jj];   // batches 0..15
            Gt[(16 + kg*4 + jj)*GPITCH + colc] = acc1[jj];   // batches 16..31
        }
        __syncthreads();   // sync1: Gt ready, At free

        // ---- restage x(s+1) (held in xr); issue prefetch x(s+2) ----
        if (s + 1 < S_){
            u16 tmp[16];
            #pragma unroll
            for (int q = 0; q < 16; ++q) tmp[q] = f2bf(xr[q]);
            *(short8*)(At + sb*APITCH + dp*16)     = *(const short8*)tmp;
            *(short8*)(At + sb*APITCH + dp*16 + 8) = *(const short8*)(tmp+8);
        }
        if (s + 2 < S_){
            const float* xp = x + ((size_t)(b0+sb)*S_ + (s+2))*H_ + dp*16;
            #pragma unroll
            for (int q = 0; q < 4; ++q){
                f32x4 v = *(const f32x4*)(xp + q*4);
                xr[q*4+0]=v[0]; xr[q*4+1]=v[1]; xr[q*4+2]=v[2]; xr[q*4+3]=v[3];
            }
        }

        // ---- cell update ----
        float hn0, hn1;
        u16* hnext = hbuf + (size_t)((s+1)&1)*(B_*H_);
        {
            const float* gr = Gt + sb*GPITCH + 2*dp;
            float iv0 = gr[0],  iv1 = gr[1];
            float fv0 = gr[32], fv1 = gr[33];
            float gv0 = gr[64], gv1 = gr[65];
            float ov0 = gr[96], ov1 = gr[97];
            float cn0 = sigm(fv0)*c0r + sigm(iv0)*tanh_(gv0);
            float cn1 = sigm(fv1)*c1r + sigm(iv1)*tanh_(gv1);
            hn0 = sigm(ov0)*tanh_(cn0);
            hn1 = sigm(ov1)*tanh_(cn1);
            c0r = cn0; c1r = cn1;
        }
        size_t o = ((size_t)(b0+sb)*S_ + s)*H_ + d0 + 2*dp;
        float2 hv; hv.x = hn0; hv.y = hn1;

        if (s == S_-1){
            *(float2*)(out + o) = hv;
            *(float2*)(out + OUTN + o) = hv;
            break;
        }

        u32 hpk = (u32)f2bf(hn0) | ((u32)f2bf(hn1) << 16);
        // publish h pair (relaxed agent store -> device coherence point)
        __hip_atomic_store((u32*)(hnext + (size_t)(b0+sb)*H_ + d0 + 2*dp), hpk,
                           __ATOMIC_RELAXED, __HIP_MEMORY_SCOPE_AGENT);
        // own slice of next A-tile straight from registers
        *(u32*)(At + sb*APITCH + H_ + d0 + 2*dp) = hpk;

        __syncthreads();   // sync2: all h stores drained (vmcnt 0 per thread)

        if (tid == 0)
            __hip_atomic_store(&flg[cl*CWG + j], (u32)(s + 1),
                               __ATOMIC_RELAXED, __HIP_MEMORY_SCOPE_AGENT);
        __builtin_amdgcn_sched_barrier(0);   // pin flag store before the filler work

        // ---- hidden work: out stores + x-part MFMA for s+1 ----
        *(float2*)(out + o) = hv;
        *(float2*)(out + OUTN + o) = hv;
        acc0 = (f32x4){bias_l, bias_l, bias_l, bias_l};
        acc1 = acc0;
        {
            const u16* ar = At + nl*APITCH + kg*8;
            #pragma unroll
            for (int kf = 0; kf < 8; ++kf){
                short8 a0 = *(const short8*)(ar + kf*32);
                short8 a1 = *(const short8*)(ar + 16*APITCH + kf*32);
                acc0 = __builtin_amdgcn_mfma_f32_16x16x32_bf16(a0, wf[kf], acc0, 0, 0, 0);
                acc1 = __builtin_amdgcn_mfma_f32_16x16x32_bf16(a1, wf[kf], acc1, 0, 0, 0);
            }
        }

        // ---- poll: all 8 WG flags >= s+1 (4 parallel u64 loads/iter) ----
        if (tid == 0){
            const u64* fp = (const u64*)(flg + cl*CWG);
            u32 tgt = (u32)(s + 1);
            int guard = 0;
            for (;;){
                u64 f0 = __hip_atomic_load(fp+0, __ATOMIC_RELAXED, __HIP_MEMORY_SCOPE_AGENT);
                u64 f1 = __hip_atomic_load(fp+1, __ATOMIC_RELAXED, __HIP_MEMORY_SCOPE_AGENT);
                u64 f2 = __hip_atomic_load(fp+2, __ATOMIC_RELAXED, __HIP_MEMORY_SCOPE_AGENT);
                u64 f3 = __hip_atomic_load(fp+3, __ATOMIC_RELAXED, __HIP_MEMORY_SCOPE_AGENT);
                bool ok = (u32)f0 >= tgt && (u32)(f0>>32) >= tgt
                       && (u32)f1 >= tgt && (u32)(f1>>32) >= tgt
                       && (u32)f2 >= tgt && (u32)(f2>>32) >= tgt
                       && (u32)f3 >= tgt && (u32)(f3>>32) >= tgt;
                if (ok) break;
                if (++guard > (1<<18)) break;   // fail loud, don't hang
            }
        }
        __syncthreads();   // sync3: WG released

        // ---- gather h(s+1) from the other 7 WGs ----
        if ((dp >> 1) != j){
            const u64* hp = (const u64*)(hnext + (size_t)(b0+sb)*H_ + dp*16);
            u64 v0 = __hip_atomic_load(hp+0, __ATOMIC_RELAXED, __HIP_MEMORY_SCOPE_AGENT);
            u64 v1 = __hip_atomic_load(hp+1, __ATOMIC_RELAXED, __HIP_MEMORY_SCOPE_AGENT);
            u64 v2 = __hip_atomic_load(hp+2, __ATOMIC_RELAXED, __HIP_MEMORY_SCOPE_AGENT);
            u64 v3 = __hip_atomic_load(hp+3, __ATOMIC_RELAXED, __HIP_MEMORY_SCOPE_AGENT);
            u64* dst = (u64*)(At + sb*APITCH + H_ + dp*16);
            dst[0] = v0; dst[1] = v1; dst[2] = v2; dst[3] = v3;
        }
        __syncthreads();   // sync4: A-tile h-cols complete for s+1
    }
}

extern "C" void kernel_launch(void* const* d_in, const int* in_sizes, int n_in,
                              void* d_out, int out_size, void* d_ws, size_t ws_size,
                              hipStream_t stream){
    const float* x   = (const float*)d_in[0];
    const float* h0  = (const float*)d_in[1];
    const float* c0  = (const float*)d_in[2];
    const float* Wih = (const float*)d_in[3];
    const float* Whh = (const float*)d_in[4];
    const float* bih = (const float*)d_in[5];
    const float* bhh = (const float*)d_in[6];

    u16*   Wc   = (u16*)d_ws;                          // 1 MB @ 0
    float* bias = (float*)((char*)d_ws + 0x100000);    // 4 KB
    u32*   flg  = (u32*)((char*)d_ws + 0x101000);      // 1 KB flags
    u16*   hbuf = (u16*)((char*)d_ws + 0x102000);      // 1 MB (double buffer)
    float* outp = (float*)d_out;

    prep_kernel<<<(G_*KW + 255)/256, 256, 0, stream>>>(Wih, Whh, bih, bhh, h0, Wc, bias, hbuf, flg);

    void* args[] = {(void*)&x, (void*)&c0, (void*)&Wc, (void*)&bias,
                    (void*)&hbuf, (void*)&flg, (void*)&outp};
    hipLaunchCooperativeKernel((void*)lstm_kernel, dim3(NCL*CWG), dim3(512), args, 0, stream);
}